// Round 1
// baseline (990.716 us; speedup 1.0000x reference)
//
#include <hip/hip_runtime.h>
#include <math.h>

#define P 128
#define RB 64

static __device__ __forceinline__ float lrelu(float x){ return x > 0.f ? x : 0.01f*x; }

// ---------------- CSR build (by dst) ----------------
__global__ void k_hist(const int* __restrict__ dst, int E, int* __restrict__ cnt){
  for(int i = blockIdx.x*blockDim.x + threadIdx.x; i < E; i += gridDim.x*blockDim.x)
    atomicAdd(&cnt[dst[i]], 1);
}

__global__ void k_scan1(const int* __restrict__ cnt, int N, int* __restrict__ off, int* __restrict__ partial){
  __shared__ int s[256];
  int t = threadIdx.x, i = blockIdx.x*256 + t;
  int v = (i < N) ? cnt[i] : 0;
  s[t] = v; __syncthreads();
  for(int o = 1; o < 256; o <<= 1){
    int x = (t >= o) ? s[t-o] : 0; __syncthreads();
    s[t] += x; __syncthreads();
  }
  if(i < N) off[i] = s[t];            // block-local inclusive scan
  if(t == 255) partial[blockIdx.x] = s[255];
}

__global__ void k_scan2(int* __restrict__ partial, int nb){
  __shared__ int s[512];
  int t = threadIdx.x;
  int v = (t < nb) ? partial[t] : 0;
  s[t] = v; __syncthreads();
  for(int o = 1; o < 512; o <<= 1){
    int x = (t >= o) ? s[t-o] : 0; __syncthreads();
    s[t] += x; __syncthreads();
  }
  if(t < nb) partial[t] = s[t] - v;   // exclusive
}

__global__ void k_scan3(const int* __restrict__ cnt, int N, int E, int* __restrict__ off, const int* __restrict__ partial){
  int i = blockIdx.x*256 + threadIdx.x;
  if(i < N) off[i] = off[i] - cnt[i] + partial[blockIdx.x];  // exclusive global
  if(i == 0) off[N] = E;
}

__global__ void k_scatter(const int* __restrict__ ei, const float* __restrict__ ea, int E,
                          const int* __restrict__ off, int* __restrict__ cur,
                          int* __restrict__ csr_src, float* __restrict__ csr_attr){
  const int* src = ei; const int* dst = ei + E;
  for(int i = blockIdx.x*blockDim.x + threadIdx.x; i < E; i += gridDim.x*blockDim.x){
    int d = dst[i];
    int p = off[d] + atomicAdd(&cur[d], 1);
    csr_src[p]  = src[i];
    csr_attr[p] = ea[i];
  }
}

// ---------------- per-node aggregations ----------------
// agg_t[n,j] = sum over in-edges of lrelu(attr*W3[j] + b3[j])
__global__ void k_aggt(const int* __restrict__ off, const float* __restrict__ csr_attr,
                       const float* __restrict__ W3, const float* __restrict__ b3,
                       float* __restrict__ X){
  int n = blockIdx.x, t = threadIdx.x;
  float w = W3[t], b = b3[t];
  int s0 = off[n], s1 = off[n+1];
  float acc = 0.f;
  for(int p = s0; p < s1; ++p) acc += lrelu(fmaf(csr_attr[p], w, b));
  X[(size_t)n*P + t] = acc;
}

// agg[n,j] = sum over in-edges of mu[src,j]
__global__ void k_agg(const int* __restrict__ off, const int* __restrict__ csr_src,
                      const float* __restrict__ mu_in, float* __restrict__ X){
  int n = blockIdx.x, t = threadIdx.x;
  int s0 = off[n], s1 = off[n+1];
  float a0 = 0.f, a1 = 0.f;
  int p = s0;
  for(; p + 1 < s1; p += 2){
    int u = csr_src[p], v = csr_src[p+1];
    a0 += mu_in[(size_t)u*P + t];
    a1 += mu_in[(size_t)v*P + t];
  }
  if(p < s1) a0 += mu_in[(size_t)csr_src[p]*P + t];
  X[(size_t)n*P + t] = a0 + a1;
}

// ---------------- GEMM (N x 128) @ (128 x 128) with fused epilogue ----------------
// MODE 0: Out = lrelu(In@W + base)
// MODE 1: Out = In@W + b2 + b1 + type_add(row)      (builds "base")
static __device__ __forceinline__ float4 f4_fma(float s, float4 a, float4 c){
  c.x = fmaf(s, a.x, c.x); c.y = fmaf(s, a.y, c.y);
  c.z = fmaf(s, a.z, c.z); c.w = fmaf(s, a.w, c.w);
  return c;
}

template<int MODE>
__global__ __launch_bounds__(256) void k_gemm(const float* __restrict__ In, const float* __restrict__ W,
    const float* __restrict__ base, float* __restrict__ Out, int N,
    const float* __restrict__ b1, const float* __restrict__ b2,
    const float* __restrict__ xv, const float* __restrict__ Wv, const float* __restrict__ bv,
    const float* __restrict__ xp, const float* __restrict__ Wp, const float* __restrict__ bp,
    const float* __restrict__ xd, const float* __restrict__ Wd, const float* __restrict__ bd,
    int NV, int NP_){
  __shared__ float WL[64*128];    // 32 KB: half of W (k-split)
  __shared__ float ILT[128*68];   // 34.8 KB: In tile transposed [k][row], pitch 68 (pad kills bank conflicts)
  int t  = threadIdx.x;
  int tc = t & 31;                // cols j = tc*4 .. tc*4+3
  int tr = t >> 5;                // rows r = tr*8 .. tr*8+7
  int rowBase = blockIdx.x * RB;

  // load In tile (RB x 128), transposed into ILT
  {
    const float4* In4 = reinterpret_cast<const float4*>(In);
    for(int f = t; f < RB*32; f += 256){
      int row = f >> 5, c4 = f & 31;
      int rg = rowBase + row;
      float4 v = (rg < N) ? In4[(size_t)rg*32 + c4] : make_float4(0.f,0.f,0.f,0.f);
      ILT[(c4*4+0)*68 + row] = v.x;
      ILT[(c4*4+1)*68 + row] = v.y;
      ILT[(c4*4+2)*68 + row] = v.z;
      ILT[(c4*4+3)*68 + row] = v.w;
    }
  }

  float acc[8][4];
  #pragma unroll
  for(int r = 0; r < 8; r++)
    #pragma unroll
    for(int c = 0; c < 4; c++) acc[r][c] = 0.f;

  const float4* W4 = reinterpret_cast<const float4*>(W);
  for(int kb = 0; kb < 2; ++kb){
    __syncthreads();
    float4* WL4 = reinterpret_cast<float4*>(WL);
    for(int f = t; f < 64*32; f += 256){
      int kr = f >> 5, c4 = f & 31;
      WL4[f] = W4[(size_t)(kb*64 + kr)*32 + c4];
    }
    __syncthreads();
    #pragma unroll 4
    for(int k = 0; k < 64; ++k){
      float4 w  = reinterpret_cast<float4*>(WL)[k*32 + tc];
      int kg = kb*64 + k;
      float4 iA = *reinterpret_cast<const float4*>(&ILT[kg*68 + tr*8]);
      float4 iB = *reinterpret_cast<const float4*>(&ILT[kg*68 + tr*8 + 4]);
      float ir[8] = {iA.x, iA.y, iA.z, iA.w, iB.x, iB.y, iB.z, iB.w};
      #pragma unroll
      for(int r = 0; r < 8; r++){
        acc[r][0] = fmaf(ir[r], w.x, acc[r][0]);
        acc[r][1] = fmaf(ir[r], w.y, acc[r][1]);
        acc[r][2] = fmaf(ir[r], w.z, acc[r][2]);
        acc[r][3] = fmaf(ir[r], w.w, acc[r][3]);
      }
    }
  }

  int j4 = tc;  // float4 column index
  #pragma unroll
  for(int r = 0; r < 8; r++){
    int rg = rowBase + tr*8 + r;
    if(rg >= N) continue;
    float4 o;
    if(MODE == 0){
      float4 bs = reinterpret_cast<const float4*>(base)[(size_t)rg*32 + j4];
      o.x = lrelu(acc[r][0] + bs.x);
      o.y = lrelu(acc[r][1] + bs.y);
      o.z = lrelu(acc[r][2] + bs.z);
      o.w = lrelu(acc[r][3] + bs.w);
    } else {
      float4 v1 = reinterpret_cast<const float4*>(b1)[j4];
      float4 v2 = reinterpret_cast<const float4*>(b2)[j4];
      float4 ta;
      if(rg < NV){
        float x0 = xv[2*rg], x1 = xv[2*rg+1];
        float4 w0 = reinterpret_cast<const float4*>(Wv)[j4];
        float4 w1 = reinterpret_cast<const float4*>(Wv + 128)[j4];
        ta = reinterpret_cast<const float4*>(bv)[j4];
        ta = f4_fma(x0, w0, ta); ta = f4_fma(x1, w1, ta);
      } else if(rg < NV + NP_){
        int i = rg - NV;
        float x0 = xp[3*i], x1 = xp[3*i+1], x2 = xp[3*i+2];
        float4 w0 = reinterpret_cast<const float4*>(Wp)[j4];
        float4 w1 = reinterpret_cast<const float4*>(Wp + 128)[j4];
        float4 w2 = reinterpret_cast<const float4*>(Wp + 256)[j4];
        ta = reinterpret_cast<const float4*>(bp)[j4];
        ta = f4_fma(x0, w0, ta); ta = f4_fma(x1, w1, ta); ta = f4_fma(x2, w2, ta);
      } else {
        int i = rg - NV - NP_;
        float x0 = xd[2*i], x1 = xd[2*i+1];
        float4 w0 = reinterpret_cast<const float4*>(Wd)[j4];
        float4 w1 = reinterpret_cast<const float4*>(Wd + 128)[j4];
        ta = reinterpret_cast<const float4*>(bd)[j4];
        ta = f4_fma(x0, w0, ta); ta = f4_fma(x1, w1, ta);
      }
      o.x = acc[r][0] + v1.x + v2.x + ta.x;
      o.y = acc[r][1] + v1.y + v2.y + ta.y;
      o.z = acc[r][2] + v1.z + v2.z + ta.z;
      o.w = acc[r][3] + v1.w + v2.w + ta.w;
    }
    reinterpret_cast<float4*>(Out)[(size_t)rg*32 + j4] = o;
  }
}

// ---------------- per-graph mean + sigmoid head ----------------
__global__ void k_final(const float* __restrict__ mu, const int* __restrict__ batch, int N,
                        const float* __restrict__ Wc, const float* __restrict__ bc,
                        float* __restrict__ out){
  int g = blockIdx.x, t = threadIdx.x;
  int lo = 0, hi = N;
  while(lo < hi){ int m = (lo+hi) >> 1; if(batch[m] < g) lo = m+1; else hi = m; }
  int start = lo;
  lo = start; hi = N;
  while(lo < hi){ int m = (lo+hi) >> 1; if(batch[m] < g+1) lo = m+1; else hi = m; }
  int end = lo;
  float a0=0.f, a1=0.f, a2=0.f, a3=0.f;
  int n = start;
  for(; n + 3 < end; n += 4){
    a0 += mu[(size_t)n*P + t];
    a1 += mu[(size_t)(n+1)*P + t];
    a2 += mu[(size_t)(n+2)*P + t];
    a3 += mu[(size_t)(n+3)*P + t];
  }
  for(; n < end; ++n) a0 += mu[(size_t)n*P + t];
  float cntf = (float)(end - start); if(cntf < 1.f) cntf = 1.f;
  float gv = (a0 + a1 + a2 + a3) / cntf;
  __shared__ float red[128];
  red[t] = gv * Wc[t];
  __syncthreads();
  for(int o = 64; o > 0; o >>= 1){
    if(t < o) red[t] += red[t + o];
    __syncthreads();
  }
  if(t == 0){
    float v = red[0] + bc[0];
    out[g] = 1.f / (1.f + expf(-v));
  }
}

extern "C" void kernel_launch(void* const* d_in, const int* in_sizes, int n_in,
                              void* d_out, int out_size, void* d_ws, size_t ws_size,
                              hipStream_t stream){
  const float* edge_attr = (const float*)d_in[0];
  const float* node_mu   = (const float*)d_in[1];
  const float* xv = (const float*)d_in[2];
  const float* xp = (const float*)d_in[3];
  const float* xd = (const float*)d_in[4];
  const float* W1 = (const float*)d_in[5];  const float* b1 = (const float*)d_in[6];
  const float* W2 = (const float*)d_in[7];  const float* b2 = (const float*)d_in[8];
  const float* W3 = (const float*)d_in[9];  const float* b3 = (const float*)d_in[10];
  const float* Wv = (const float*)d_in[11]; const float* bv = (const float*)d_in[12];
  const float* Wp = (const float*)d_in[13]; const float* bp = (const float*)d_in[14];
  const float* Wd = (const float*)d_in[15]; const float* bd = (const float*)d_in[16];
  const float* Wc = (const float*)d_in[17]; const float* bc = (const float*)d_in[18];
  const int*   ei    = (const int*)d_in[19];
  const int*   batch = (const int*)d_in[21];
  const int E   = in_sizes[0];
  const int N   = in_sizes[1] / P;
  const int NV  = in_sizes[2] / 2;
  const int NP_ = in_sizes[3] / 3;
  const int G   = 64;   // num_graphs is a fixed scalar (=64) in this problem
  float* out = (float*)d_out;

  char* w = (char*)d_ws; size_t o = 0;
  auto alloc = [&](size_t bytes)->void*{ size_t a = (o + 255) & ~(size_t)255; o = a + bytes; return (void*)(w + a); };
  int*   cnt      = (int*)  alloc((size_t)N*4);
  int*   cur      = (int*)  alloc((size_t)N*4);
  int*   off      = (int*)  alloc((size_t)(N+1)*4);
  int*   partial  = (int*)  alloc(512*4);
  int*   csr_src  = (int*)  alloc((size_t)E*4);
  float* csr_attr = (float*)alloc((size_t)E*4);
  float* X    = (float*)alloc((size_t)N*P*4);   // agg scratch
  float* Y    = (float*)alloc((size_t)N*P*4);   // mu
  float* base = (float*)alloc((size_t)N*P*4);   // b1 + t_term + type_add

  hipMemsetAsync(cnt, 0, (size_t)N*4, stream);
  hipMemsetAsync(cur, 0, (size_t)N*4, stream);

  int nb = (N + 255) / 256;   // 387 <= 512, fits k_scan2
  k_hist   <<<2048, 256, 0, stream>>>(ei + E, E, cnt);
  k_scan1  <<<nb,   256, 0, stream>>>(cnt, N, off, partial);
  k_scan2  <<<1,    512, 0, stream>>>(partial, nb);
  k_scan3  <<<nb,   256, 0, stream>>>(cnt, N, E, off, partial);
  k_scatter<<<2048, 256, 0, stream>>>(ei, edge_attr, E, off, cur, csr_src, csr_attr);

  k_aggt<<<N, P, 0, stream>>>(off, csr_attr, W3, b3, X);
  int gb = (N + RB - 1) / RB;
  k_gemm<1><<<gb, 256, 0, stream>>>(X, W2, nullptr, base, N, b1, b2,
                                    xv, Wv, bv, xp, Wp, bp, xd, Wd, bd, NV, NP_);

  const float* muin = node_mu;
  for(int r = 0; r < 4; ++r){
    k_agg<<<N, P, 0, stream>>>(off, csr_src, muin, X);
    k_gemm<0><<<gb, 256, 0, stream>>>(X, W1, base, Y, N, b1, b2,
                                      xv, Wv, bv, xp, Wp, bp, xd, Wd, bd, NV, NP_);
    muin = Y;
  }

  k_final<<<G, P, 0, stream>>>(Y, batch, N, Wc, bc, out);
}

// Round 2
// 796.984 us; speedup vs baseline: 1.2431x; 1.2431x over previous
//
#include <hip/hip_runtime.h>
#include <math.h>

#define P 128

typedef __attribute__((ext_vector_type(8))) short short8;
typedef __attribute__((ext_vector_type(4))) float f32x4;

static __device__ __forceinline__ float lrelu(float x){ return x > 0.f ? x : 0.01f*x; }
static __device__ __forceinline__ float bflo(unsigned u){ union{unsigned u; float f;} c; c.u = u << 16; return c.f; }
static __device__ __forceinline__ float bfhi(unsigned u){ union{unsigned u; float f;} c; c.u = u & 0xffff0000u; return c.f; }
static __device__ __forceinline__ unsigned fbits(float f){ union{float f; unsigned u;} c; c.f = f; return c.u; }
// round-to-nearest-even f32->bf16, packed pair
static __device__ __forceinline__ unsigned packbf(float x, float y){
  unsigned ux = fbits(x); ux += 0x7fffu + ((ux >> 16) & 1u);
  unsigned uy = fbits(y); uy += 0x7fffu + ((uy >> 16) & 1u);
  return (ux >> 16) | (uy & 0xffff0000u);
}

// ---------------- CSR build (by dst) ----------------
__global__ void k_hist(const int* __restrict__ dst, int E, int* __restrict__ cnt){
  for(int i = blockIdx.x*blockDim.x + threadIdx.x; i < E; i += gridDim.x*blockDim.x)
    atomicAdd(&cnt[dst[i]], 1);
}

__global__ void k_scan1(const int* __restrict__ cnt, int N, int* __restrict__ off, int* __restrict__ partial){
  __shared__ int s[256];
  int t = threadIdx.x, i = blockIdx.x*256 + t;
  int v = (i < N) ? cnt[i] : 0;
  s[t] = v; __syncthreads();
  for(int o = 1; o < 256; o <<= 1){
    int x = (t >= o) ? s[t-o] : 0; __syncthreads();
    s[t] += x; __syncthreads();
  }
  if(i < N) off[i] = s[t];
  if(t == 255) partial[blockIdx.x] = s[255];
}

__global__ void k_scan2(int* __restrict__ partial, int nb){
  __shared__ int s[512];
  int t = threadIdx.x;
  int v = (t < nb) ? partial[t] : 0;
  s[t] = v; __syncthreads();
  for(int o = 1; o < 512; o <<= 1){
    int x = (t >= o) ? s[t-o] : 0; __syncthreads();
    s[t] += x; __syncthreads();
  }
  if(t < nb) partial[t] = s[t] - v;
}

__global__ void k_scan3(const int* __restrict__ cnt, int N, int E, int* __restrict__ off, const int* __restrict__ partial){
  int i = blockIdx.x*256 + threadIdx.x;
  if(i < N) off[i] = off[i] - cnt[i] + partial[blockIdx.x];
  if(i == 0) off[N] = E;
}

__global__ void k_scatter(const int* __restrict__ ei, const float* __restrict__ ea, int E,
                          const int* __restrict__ off, int* __restrict__ cur,
                          int* __restrict__ csr_src, float* __restrict__ csr_attr){
  const int* src = ei; const int* dst = ei + E;
  for(int i = blockIdx.x*blockDim.x + threadIdx.x; i < E; i += gridDim.x*blockDim.x){
    int d = dst[i];
    int p = off[d] + atomicAdd(&cur[d], 1);
    csr_src[p]  = src[i];
    csr_attr[p] = ea[i];
  }
}

// ---------------- converters ----------------
__global__ void k_cvt(const float2* __restrict__ in, unsigned* __restrict__ out, int n){
  int i = blockIdx.x*256 + threadIdx.x;
  if(i < n){ float2 v = in[i]; out[i] = packbf(v.x, v.y); }
}

// WT_bf16[j][k] = W[k][j]; one block per j (128 blocks x 64 threads)
__global__ void k_trans(const float* __restrict__ W, unsigned* __restrict__ WT){
  int j = blockIdx.x, k2 = threadIdx.x;
  float a = W[(size_t)(2*k2)*P + j], b = W[(size_t)(2*k2+1)*P + j];
  WT[(size_t)j*64 + k2] = packbf(a, b);
}

// base0[n][:] = b1 + b2 + type_add(n)  (bf16)
__global__ __launch_bounds__(256) void k_typeadd(
    const float* __restrict__ xv, const float* __restrict__ Wv, const float* __restrict__ bv,
    const float* __restrict__ xp, const float* __restrict__ Wp, const float* __restrict__ bp,
    const float* __restrict__ xd, const float* __restrict__ Wd, const float* __restrict__ bd,
    const float* __restrict__ b1, const float* __restrict__ b2,
    int NV, int NP_, int N, unsigned* __restrict__ base0){
  int idx = blockIdx.x*256 + threadIdx.x;
  if(idx >= N*4) return;
  int n = idx >> 2, c0 = (idx & 3)*32;
  const float *Wt, *bt; float x0, x1, x2; int ni;
  if(n < NV){ Wt=Wv; bt=bv; x0=xv[2*n]; x1=xv[2*n+1]; x2=0.f; ni=2; }
  else if(n < NV+NP_){ int i=n-NV; Wt=Wp; bt=bp; x0=xp[3*i]; x1=xp[3*i+1]; x2=xp[3*i+2]; ni=3; }
  else { int i=n-NV-NP_; Wt=Wd; bt=bd; x0=xd[2*i]; x1=xd[2*i+1]; x2=0.f; ni=2; }
  unsigned o[16];
  #pragma unroll
  for(int i = 0; i < 16; ++i){
    int c = c0 + 2*i;
    float f0 = b1[c]   + b2[c]   + bt[c]   + x0*Wt[c]   + x1*Wt[P+c];
    float f1 = b1[c+1] + b2[c+1] + bt[c+1] + x0*Wt[c+1] + x1*Wt[P+c+1];
    if(ni == 3){ f0 += x2*Wt[2*P+c]; f1 += x2*Wt[2*P+c+1]; }
    o[i] = packbf(f0, f1);
  }
  uint4* dst = (uint4*)(base0 + (size_t)n*64 + c0/2);
  #pragma unroll
  for(int q = 0; q < 4; ++q) dst[q] = make_uint4(o[4*q], o[4*q+1], o[4*q+2], o[4*q+3]);
}

// ---------------- per-node aggregations (1 wave per node) ----------------
__global__ void k_aggt(const int* __restrict__ off, const float* __restrict__ csr_attr,
                       const float* __restrict__ W3, const float* __restrict__ b3,
                       unsigned* __restrict__ X, int N){
  int node = blockIdx.x*4 + (threadIdx.x >> 6);
  if(node >= N) return;
  int lane = threadIdx.x & 63;
  float w0 = W3[2*lane], w1 = W3[2*lane+1];
  float c0 = b3[2*lane], c1 = b3[2*lane+1];
  int s0 = off[node], s1 = off[node+1];
  float a0 = 0.f, a1 = 0.f;
  for(int p = s0; p < s1; ++p){
    float a = csr_attr[p];
    a0 += lrelu(fmaf(a, w0, c0));
    a1 += lrelu(fmaf(a, w1, c1));
  }
  X[(size_t)node*64 + lane] = packbf(a0, a1);
}

__global__ void k_agg(const int* __restrict__ off, const int* __restrict__ csr_src,
                      const unsigned* __restrict__ mu, unsigned* __restrict__ X, int N){
  int node = blockIdx.x*4 + (threadIdx.x >> 6);
  if(node >= N) return;
  int lane = threadIdx.x & 63;
  int s0 = off[node], s1 = off[node+1];
  float x0=0.f, y0=0.f, x1=0.f, y1=0.f;
  int p = s0;
  for(; p+1 < s1; p += 2){
    unsigned v0 = mu[(size_t)csr_src[p]*64 + lane];
    unsigned v1 = mu[(size_t)csr_src[p+1]*64 + lane];
    x0 += bflo(v0); y0 += bfhi(v0);
    x1 += bflo(v1); y1 += bfhi(v1);
  }
  if(p < s1){
    unsigned v = mu[(size_t)csr_src[p]*64 + lane];
    x0 += bflo(v); y0 += bfhi(v);
  }
  X[(size_t)node*64 + lane] = packbf(x0+x1, y0+y1);
}

// ---------------- MFMA GEMM: Out = [lrelu](A @ W^T + addv), all bf16, fp32 acc ----
// block: 256 threads = 4 waves; 64 rows x 128 cols per block.
template<int ACT>
__global__ __launch_bounds__(256) void k_gemm(const short8* __restrict__ A, const short8* __restrict__ WT,
    const unsigned* __restrict__ addv, unsigned* __restrict__ Out, int N){
  __shared__ float sh[64*132];
  int t = threadIdx.x;
  int w = t >> 6, l = t & 63;
  int lr = l & 15, lg = l >> 4;
  int bm = blockIdx.x * 64;
  f32x4 acc[8];
  #pragma unroll
  for(int i = 0; i < 8; ++i) acc[i] = (f32x4)0.f;
  int arow = bm + w*16 + lr;     // reads may overrun by <8 rows in last block: lands in next ws buffer (safe)
  #pragma unroll
  for(int ks = 0; ks < 4; ++ks){
    short8 a = A[(size_t)arow*16 + ks*4 + lg];
    #pragma unroll
    for(int ct = 0; ct < 8; ++ct){
      short8 b = WT[(size_t)(ct*16 + lr)*16 + ks*4 + lg];
      acc[ct] = __builtin_amdgcn_mfma_f32_16x16x32_bf16(a, b, acc[ct], 0, 0, 0);
    }
  }
  // C/D layout: col = lane&15, row = (lane>>4)*4 + reg   [m89-verified]
  #pragma unroll
  for(int ct = 0; ct < 8; ++ct)
    #pragma unroll
    for(int r = 0; r < 4; ++r)
      sh[(w*16 + lg*4 + r)*132 + ct*16 + lr] = acc[ct][r];
  __syncthreads();
  int r = t >> 2, seg = t & 3;
  int row = bm + r;
  if(row >= N) return;
  unsigned o[16];
  const float* s = &sh[r*132 + seg*32];
  const unsigned* ad = addv + (size_t)row*64 + seg*16;
  #pragma unroll
  for(int i = 0; i < 16; ++i){
    unsigned b = ad[i];
    float f0 = s[2*i]   + bflo(b);
    float f1 = s[2*i+1] + bfhi(b);
    if(ACT){ f0 = lrelu(f0); f1 = lrelu(f1); }
    o[i] = packbf(f0, f1);
  }
  uint4* dst = (uint4*)(Out + (size_t)row*64 + seg*16);
  #pragma unroll
  for(int q = 0; q < 4; ++q) dst[q] = make_uint4(o[4*q], o[4*q+1], o[4*q+2], o[4*q+3]);
}

// ---------------- two-stage graph mean + sigmoid head ----------------
#define GSB 256
__global__ void k_gsum(const unsigned* __restrict__ mu, const int* __restrict__ batch, int N,
                       float* __restrict__ gsum){
  int c = threadIdx.x & 63, sub = threadIdx.x >> 6;
  int n0 = blockIdx.x * GSB;
  int n1 = min(n0 + GSB, N);
  float ax = 0.f, ay = 0.f; int curg = -1;
  for(int n = n0 + sub; n < n1; n += 4){
    int g = batch[n];
    if(g != curg){
      if(curg >= 0){ atomicAdd(&gsum[curg*P + 2*c], ax); atomicAdd(&gsum[curg*P + 2*c + 1], ay); }
      curg = g; ax = 0.f; ay = 0.f;
    }
    unsigned v = mu[(size_t)n*64 + c];
    ax += bflo(v); ay += bfhi(v);
  }
  if(curg >= 0){ atomicAdd(&gsum[curg*P + 2*c], ax); atomicAdd(&gsum[curg*P + 2*c + 1], ay); }
}

__global__ void k_out(const float* __restrict__ gsum, const int* __restrict__ batch, int N,
                      const float* __restrict__ Wc, const float* __restrict__ bc,
                      float* __restrict__ out){
  int g = blockIdx.x, t = threadIdx.x;
  int lo = 0, hi = N;
  while(lo < hi){ int m=(lo+hi)>>1; if(batch[m] < g) lo = m+1; else hi = m; }
  int start = lo; lo = start; hi = N;
  while(lo < hi){ int m=(lo+hi)>>1; if(batch[m] <= g) lo = m+1; else hi = m; }
  int cnt = lo - start;
  float cf = cnt < 1 ? 1.f : (float)cnt;
  __shared__ float red[128];
  red[t] = (gsum[g*P + t] / cf) * Wc[t];
  __syncthreads();
  for(int o = 64; o > 0; o >>= 1){ if(t < o) red[t] += red[t+o]; __syncthreads(); }
  if(t == 0) out[g] = 1.f/(1.f + expf(-(red[0] + bc[0])));
}

extern "C" void kernel_launch(void* const* d_in, const int* in_sizes, int n_in,
                              void* d_out, int out_size, void* d_ws, size_t ws_size,
                              hipStream_t stream){
  const float* edge_attr = (const float*)d_in[0];
  const float* node_mu   = (const float*)d_in[1];
  const float* xv = (const float*)d_in[2];
  const float* xp = (const float*)d_in[3];
  const float* xd = (const float*)d_in[4];
  const float* W1 = (const float*)d_in[5];  const float* b1 = (const float*)d_in[6];
  const float* W2 = (const float*)d_in[7];  const float* b2 = (const float*)d_in[8];
  const float* W3 = (const float*)d_in[9];  const float* b3 = (const float*)d_in[10];
  const float* Wv = (const float*)d_in[11]; const float* bv = (const float*)d_in[12];
  const float* Wp = (const float*)d_in[13]; const float* bp = (const float*)d_in[14];
  const float* Wd = (const float*)d_in[15]; const float* bd = (const float*)d_in[16];
  const float* Wc = (const float*)d_in[17]; const float* bc = (const float*)d_in[18];
  const int*   ei    = (const int*)d_in[19];
  const int*   batch = (const int*)d_in[21];
  const int E   = in_sizes[0];
  const int N   = in_sizes[1] / P;
  const int NV  = in_sizes[2] / 2;
  const int NP_ = in_sizes[3] / 3;
  const int G   = 64;
  float* out = (float*)d_out;

  char* w = (char*)d_ws; size_t o = 0;
  auto alloc = [&](size_t bytes)->void*{ size_t a = (o + 255) & ~(size_t)255; o = a + bytes; return (void*)(w + a); };
  int*      cnt      = (int*)     alloc((size_t)N*4);
  int*      cur      = (int*)     alloc((size_t)N*4);
  int*      off      = (int*)     alloc((size_t)(N+1)*4);
  int*      partial  = (int*)     alloc(512*4);
  int*      csr_src  = (int*)     alloc((size_t)E*4);
  float*    csr_attr = (float*)   alloc((size_t)E*4);
  unsigned* mu0      = (unsigned*)alloc((size_t)N*64*4);   // bf16 pairs
  unsigned* X        = (unsigned*)alloc((size_t)N*64*4);   // agg scratch (bf16)
  unsigned* Y        = (unsigned*)alloc((size_t)N*64*4);   // mu (bf16)
  unsigned* base0    = (unsigned*)alloc((size_t)N*64*4);   // b1+b2+type_add
  unsigned* baseB    = (unsigned*)alloc((size_t)N*64*4);   // + t_term
  unsigned* W1T      = (unsigned*)alloc((size_t)P*64*4);
  unsigned* W2T      = (unsigned*)alloc((size_t)P*64*4);
  float*    gsum     = (float*)   alloc((size_t)G*P*4);
  (void)alloc(4096); // slack for last-block A overreads

  hipMemsetAsync(cnt,  0, (size_t)N*4, stream);
  hipMemsetAsync(cur,  0, (size_t)N*4, stream);
  hipMemsetAsync(gsum, 0, (size_t)G*P*4, stream);

  int nb = (N + 255) / 256;
  k_hist   <<<2048, 256, 0, stream>>>(ei + E, E, cnt);
  k_scan1  <<<nb,   256, 0, stream>>>(cnt, N, off, partial);
  k_scan2  <<<1,    512, 0, stream>>>(partial, nb);
  k_scan3  <<<nb,   256, 0, stream>>>(cnt, N, E, off, partial);
  k_scatter<<<2048, 256, 0, stream>>>(ei, edge_attr, E, off, cur, csr_src, csr_attr);

  int nhalf = N*64;
  k_cvt  <<<(nhalf + 255)/256, 256, 0, stream>>>((const float2*)node_mu, mu0, nhalf);
  k_trans<<<P, 64, 0, stream>>>(W1, W1T);
  k_trans<<<P, 64, 0, stream>>>(W2, W2T);
  k_typeadd<<<(N*4 + 255)/256, 256, 0, stream>>>(xv, Wv, bv, xp, Wp, bp, xd, Wd, bd,
                                                 b1, b2, NV, NP_, N, base0);

  int gagg = (N + 3) / 4;
  int ggemm = (N + 63) / 64;
  k_aggt<<<gagg, 256, 0, stream>>>(off, csr_attr, W3, b3, X, N);
  k_gemm<0><<<ggemm, 256, 0, stream>>>((const short8*)X, (const short8*)W2T, base0, baseB, N);

  const unsigned* muin = mu0;
  for(int r = 0; r < 4; ++r){
    k_agg<<<gagg, 256, 0, stream>>>(off, csr_src, muin, X, N);
    k_gemm<1><<<ggemm, 256, 0, stream>>>((const short8*)X, (const short8*)W1T, baseB, Y, N);
    muin = Y;
  }

  k_gsum<<<(N + GSB - 1)/GSB, 256, 0, stream>>>(Y, batch, N, gsum);
  k_out <<<G, P, 0, stream>>>(gsum, batch, N, Wc, bc, out);
}